// Round 6
// baseline (111.807 us; speedup 1.0000x reference)
//
#include <hip/hip_runtime.h>

// ScaledDotProductAttention B=8, L=2048, D=64, fp32 in/out.
//
// R19: two-phase frag structure + intra-block LDS sharing of the frag stream.
// Evidence trail: attn is invariant at ~27-29 us across R0/R4/R18 and tracks
// ISSUED frag bytes (R0 268 MB @4w/SIMD ~27us, R4 134 MB @2w ~29us, R18
// 268 MB @4w ~27us) at ~10 TB/s effective -- LLC rate, not L2. The qg pair of
// each kg re-issues identical loads; dedupe them through LDS:
//  1) prepass_frag (unchanged from R18): K/V -> f16 MFMA frags in ws,
//     XCD-aligned (b=blk&7), V ks-paired so consume is 4x b128 per tile.
//  2) attn_shared: 256 blocks x 1024 thr = 16 waves = kg(8) x qg(2),
//     1 blk/CU, 4 waves/SIMD (VGPR ~100: no persistent K/V frag regs).
//     Per step tt (8 steps): block stages 64 KB (8 kg-tiles x (K 4KB|V 4KB))
//     into LDS as a pure b128 memcpy (4 x 16B per thread; frag bytes are
//     already final layout), double-buffered in 128 KB LDS. T14 order:
//     { SSWRITE(tt+1)->buf^1; SGLOAD(tt+2)->regs; PROCL(buf); barrier }.
//     Issued global frag traffic 268 -> 134 MB at unchanged occupancy.
//     Consume = R18 PROC verbatim (swapped QK^T, exp2 with folded scale,
//     packed half4 P as B-frag of mfma_16x16x16f16, ks-paired V A-frags).
//     Epilogue = R18's verified 16-wave (O,l) combine, aliasing the frag LDS.
// Fallback: proven R3 kernel if ws too small.

#define B_ 8
#define L_ 2048
#define D_ 64
#define NT 256

typedef _Float16 half8_t __attribute__((ext_vector_type(8)));
typedef _Float16 half4_t __attribute__((ext_vector_type(4)));
typedef float f32x4 __attribute__((ext_vector_type(4)));

#define SCALE_LOG2E 0.1803368801111244f   // 0.125 * log2(e)

// ------------------------------------------------------------ prepass_frag --
// blocks 0..511: K fragments; 512..1023: V^T fragments. XCD-aligned batches.
__global__ __launch_bounds__(NT) void prepass_frag(
    const float* __restrict__ K, const float* __restrict__ V,
    _Float16* __restrict__ K16F, _Float16* __restrict__ VT16F)
{
    const int blk = blockIdx.x;
    const int t = threadIdx.x;
    if (blk < 512) {
        const int b  = blk & 7;           // XCD-aligned (blk%8 -> XCD)
        const int kt = blk >> 3;          // 0..63
        const int p    = t >> 6;          // plane = s*2 + c
        const int lane = t & 63;
        const int quad = lane >> 4;
        const int l15  = lane & 15;
        const int s = p >> 1, c = p & 1;
        const int row = kt * 32 + s * 16 + l15;
        const float* kp = K + ((size_t)b * L_ + row) * D_ + c * 32 + quad * 8;
        const float4 f0 = *(const float4*)kp;
        const float4 f1 = *(const float4*)(kp + 4);
        half8_t w;
        w[0] = (_Float16)f0.x; w[1] = (_Float16)f0.y;
        w[2] = (_Float16)f0.z; w[3] = (_Float16)f0.w;
        w[4] = (_Float16)f1.x; w[5] = (_Float16)f1.y;
        w[6] = (_Float16)f1.z; w[7] = (_Float16)f1.w;
        *(half8_t*)&K16F[((size_t)(b * 64 + kt) * 4 + p) * 512 + lane * 8] = w;
    } else {
        const int vb = blk - 512;
        const int b  = vb & 7;            // XCD-aligned
        const int kt = vb >> 3;
        #pragma unroll
        for (int i = 0; i < 2; ++i) {
            const int slot = i * NT + t;      // 512 slots = 8 planes x 64 lanes
            const int p    = slot >> 6;       // plane = d*2 + ks
            const int lane = slot & 63;
            const int quad = lane >> 4;
            const int l15  = lane & 15;
            const int d = p >> 1, ks = p & 1;
            const int row = kt * 32 + ks * 16 + quad * 4;
            const int col = d * 16 + l15;
            const float* vp = V + ((size_t)b * L_ + row) * D_ + col;
            half4_t a;
            a[0] = (_Float16)vp[0];
            a[1] = (_Float16)vp[D_];
            a[2] = (_Float16)vp[2 * D_];
            a[3] = (_Float16)vp[3 * D_];
            // ks-paired layout: one b128 per (tile,d) at consume time
            *(half4_t*)&VT16F[((size_t)(b * 64 + kt) * 4 + d) * 512 + lane * 8 + ks * 4] = a;
        }
    }
}

// ------------------------------------------------------------ attn_shared --

// consume one tile per kg from LDS buf at half-offset CB (R18 PROC, LDS src)
#define PROCL(CB)                                                               \
    {                                                                           \
        const _Float16* Kt = &FR[(CB) + kg * 4096];                             \
        const _Float16* Vt = Kt + 2048;                                         \
        half8_t bk[2][2];                                                       \
        _Pragma("unroll") for (int s = 0; s < 2; ++s)                           \
        _Pragma("unroll") for (int c = 0; c < 2; ++c)                           \
            bk[s][c] = *(const half8_t*)&Kt[(s * 2 + c) * 512 + lane * 8];      \
        half4_t pb[2][2];                                                       \
        _Pragma("unroll") for (int ks = 0; ks < 2; ++ks)                        \
        _Pragma("unroll") for (int qs = 0; qs < 2; ++qs) {                      \
            f32x4 acc = (f32x4){0.f, 0.f, 0.f, 0.f};                            \
            acc = __builtin_amdgcn_mfma_f32_16x16x32_f16(bk[ks][0], bq[qs][0], acc, 0, 0, 0); \
            acc = __builtin_amdgcn_mfma_f32_16x16x32_f16(bk[ks][1], bq[qs][1], acc, 0, 0, 0); \
            const float p0 = __builtin_exp2f(acc[0]);                           \
            const float p1 = __builtin_exp2f(acc[1]);                           \
            const float p2 = __builtin_exp2f(acc[2]);                           \
            const float p3 = __builtin_exp2f(acc[3]);                           \
            lacc[qs] += (p0 + p1) + (p2 + p3);                                  \
            half4_t pv;                                                         \
            pv[0] = (_Float16)p0; pv[1] = (_Float16)p1;                         \
            pv[2] = (_Float16)p2; pv[3] = (_Float16)p3;                         \
            pb[ks][qs] = pv;                                                    \
        }                                                                       \
        _Pragma("unroll") for (int d = 0; d < 4; ++d) {                         \
            const half8_t av8 = *(const half8_t*)&Vt[d * 512 + lane * 8];       \
            const half4_t alo = __builtin_shufflevector(av8, av8, 0, 1, 2, 3);  \
            const half4_t ahi = __builtin_shufflevector(av8, av8, 4, 5, 6, 7);  \
            _Pragma("unroll") for (int qs = 0; qs < 2; ++qs) {                  \
                ofr[qs][d] = __builtin_amdgcn_mfma_f32_16x16x16f16(alo, pb[0][qs], ofr[qs][d], 0, 0, 0); \
                ofr[qs][d] = __builtin_amdgcn_mfma_f32_16x16x16f16(ahi, pb[1][qs], ofr[qs][d], 0, 0, 0); \
            }                                                                   \
        }                                                                       \
    }

// staging: thread copies 4 x 16B; sources advance by tt*2048 halfs per step
#define SGLOAD(TT)                                                              \
    _Pragma("unroll") for (int j = 0; j < 4; ++j)                               \
        kf[j] = *(const float4*)(sb[j] + (size_t)(TT) * 2048);

#define SSWRITE(BUF)                                                            \
    _Pragma("unroll") for (int j = 0; j < 4; ++j)                               \
        *(float4*)&FR[(BUF) * 32768 + sdst[j]] = kf[j];

__global__ __launch_bounds__(1024) void attn_shared(
    const float* __restrict__ Q,
    const _Float16* __restrict__ K16F,
    const _Float16* __restrict__ VT16F,
    float* __restrict__ O)
{
    // 2 bufs x 8 kg x (K 2048 | V 2048 halfs) = 65536 halfs = 128 KB.
    // Epilogue aliases this as float Ored[17408] + float Lred[512].
    __shared__ __align__(16) _Float16 FR[65536];

    const int t    = threadIdx.x;
    const int wave = t >> 6;                   // 0..15
    const int lane = t & 63;
    const int quad = lane >> 4;
    const int l15  = lane & 15;
    const int kg   = wave >> 1;                // key range [kg*256, +256)
    const int qg   = wave & 1;                 // query half (32 queries)

    const int b   = blockIdx.x & 7;            // batch <-> XCD affinity
    const int qbi = blockIdx.x >> 3;           // query block 0..31
    const int qb  = qbi * 64;
    const int q0  = qb + qg * 32;

    const _Float16* KbF = K16F + (size_t)b * 64 * 4 * 512;
    const _Float16* VbF = VT16F + (size_t)b * 64 * 4 * 512;

    // ---- staging slot map: 4096 b128 slots/step; thread owns j*1024 + t ---
    // slot s: kg = s>>9, half = (s>>8)&1 (0=K,1=V), off16 = s&255.
    // LDS halfs offset = s*8; global = (half?VbF:KbF) + (kg*8+tt)*2048 + off16*8.
    const _Float16* sb[4];
    int sdst[4];
    #pragma unroll
    for (int j = 0; j < 4; ++j) {
        const int s = j * 1024 + t;
        const int skg  = s >> 9;
        const int half = (s >> 8) & 1;
        const int o16  = s & 255;
        sb[j] = (half ? VbF : KbF) + (size_t)skg * 16384 + o16 * 8;
        sdst[j] = s * 8;
    }

    // ---- Q B-frags from fp32, pre-scaled by 0.125*log2(e) ----
    half8_t bq[2][2];
    #pragma unroll
    for (int qs = 0; qs < 2; ++qs) {
        const float* qp = Q + ((size_t)b * L_ + q0 + qs * 16 + l15) * D_ + quad * 8;
        #pragma unroll
        for (int c = 0; c < 2; ++c) {
            const float4 f0 = *(const float4*)(qp + c * 32);
            const float4 f1 = *(const float4*)(qp + c * 32 + 4);
            bq[qs][c][0] = (_Float16)(f0.x * SCALE_LOG2E);
            bq[qs][c][1] = (_Float16)(f0.y * SCALE_LOG2E);
            bq[qs][c][2] = (_Float16)(f0.z * SCALE_LOG2E);
            bq[qs][c][3] = (_Float16)(f0.w * SCALE_LOG2E);
            bq[qs][c][4] = (_Float16)(f1.x * SCALE_LOG2E);
            bq[qs][c][5] = (_Float16)(f1.y * SCALE_LOG2E);
            bq[qs][c][6] = (_Float16)(f1.z * SCALE_LOG2E);
            bq[qs][c][7] = (_Float16)(f1.w * SCALE_LOG2E);
        }
    }

    f32x4 ofr[2][4];
    #pragma unroll
    for (int qs = 0; qs < 2; ++qs)
        #pragma unroll
        for (int d = 0; d < 4; ++d)
            ofr[qs][d] = (f32x4){0.f, 0.f, 0.f, 0.f};
    float lacc[2] = {0.f, 0.f};

    // ---- hot loop: 8 steps, dbuf, T14 issue-early/write-late --------------
    float4 kf[4];
    SGLOAD(0);
    SSWRITE(0);
    SGLOAD(1);
    __syncthreads();

    for (int tt = 0; tt < 8; ++tt) {
        const int cb = (tt & 1) * 32768;
        if (tt < 7) {
            SSWRITE((tt & 1) ^ 1);            // step tt+1 -> other buf
            if (tt < 6) SGLOAD(tt + 2);       // issue step tt+2 early
        }
        PROCL(cb);                            // tile kg*8 + tt
        __syncthreads();
    }

    // ---- l: reduce over quads (lane holds partial for query qs*16+l15) ----
    float lsum[2];
    #pragma unroll
    for (int qs = 0; qs < 2; ++qs) {
        float v = lacc[qs];
        v += __shfl_xor(v, 16, 64);
        v += __shfl_xor(v, 32, 64);
        lsum[qs] = v;
    }
    float* Ored = (float*)&FR[0];              // [16 waves][64 lanes][17]
    float* Lred = Ored + 17408;                // [16 waves][32]
    if (quad == 0) {
        Lred[wave * 32 + l15]      = lsum[0];
        Lred[wave * 32 + 16 + l15] = lsum[1];
    }

    // ---- cross-wave combine: 8 kg sources per qg group (R18 verbatim) -----
    #pragma unroll
    for (int qs = 0; qs < 2; ++qs) {
        __syncthreads();   // previous round's reads (and Lred writes) done
        float* dst = &Ored[(wave * 64 + lane) * 17];
        #pragma unroll
        for (int d = 0; d < 4; ++d)
            #pragma unroll
            for (int r = 0; r < 4; ++r)
                dst[d * 4 + r] = ofr[qs][d][r];
        __syncthreads();
        if (wave < 8) {
            const int rkg = wave >> 1;          // output dim block 0..3
            const int rqg = wave & 1;           // query group to reduce
            float lt = 0.f;
            #pragma unroll
            for (int k2 = 0; k2 < 8; ++k2)
                lt += Lred[(k2 * 2 + rqg) * 32 + qs * 16 + l15];
            const float inv = 1.0f / lt;
            f32x4 osum = (f32x4){0.f, 0.f, 0.f, 0.f};
            #pragma unroll
            for (int k2 = 0; k2 < 8; ++k2) {
                const float* src = &Ored[((k2 * 2 + rqg) * 64 + lane) * 17 + rkg * 4];
                osum[0] += src[0]; osum[1] += src[1];
                osum[2] += src[2]; osum[3] += src[3];
            }
            float4 outv;
            outv.x = osum[0] * inv; outv.y = osum[1] * inv;
            outv.z = osum[2] * inv; outv.w = osum[3] * inv;
            // query = qb + rqg*32 + qs*16 + l15 ; dims = rkg*16 + quad*4 .. +4
            *(float4*)&O[((size_t)b * L_ + qb + rqg * 32 + qs * 16 + l15) * D_
                         + rkg * 16 + quad * 4] = outv;
        }
    }
}

// ------------------------------------------------- fallback (R3, no ws) ----
#define KS 72
__global__ __launch_bounds__(NT) void attn_mfma_f16(
    const float* __restrict__ Q, const float* __restrict__ K,
    const float* __restrict__ V, float* __restrict__ O)
{
    __shared__ __align__(16) _Float16 Kt[64 * KS];
    __shared__ __align__(16) _Float16 Vt[D_ * KS];
    __shared__ __align__(16) _Float16 Pt[4][16 * KS];

    const int t = threadIdx.x;
    const int wave = t >> 6, lane = t & 63, quad = lane >> 4, l15 = lane & 15;
    const int bpb = L_ / 64;
    const int b = blockIdx.x / bpb;
    const int qb = (blockIdx.x % bpb) * 64 + wave * 16;
    const size_t boff = (size_t)b * L_ * D_;

    half8_t aq[2];
    {
        const float* qp = Q + boff + (size_t)(qb + l15) * D_ + quad * 8;
        #pragma unroll
        for (int c = 0; c < 2; ++c) {
            const float4* p4 = (const float4*)(qp + c * 32);
            const float4 f0 = p4[0], f1 = p4[1];
            aq[c][0] = (_Float16)f0.x; aq[c][1] = (_Float16)f0.y;
            aq[c][2] = (_Float16)f0.z; aq[c][3] = (_Float16)f0.w;
            aq[c][4] = (_Float16)f1.x; aq[c][5] = (_Float16)f1.y;
            aq[c][6] = (_Float16)f1.z; aq[c][7] = (_Float16)f1.w;
        }
    }
    f32x4 ofr[4];
    #pragma unroll
    for (int d = 0; d < 4; ++d) ofr[d] = (f32x4){0.f, 0.f, 0.f, 0.f};
    float lacc[4] = {0.f, 0.f, 0.f, 0.f};
    const int skey = t & 63, sdg = t >> 6;
    _Float16* Pw = &Pt[wave][0];

    for (int kt = 0; kt < L_ / 64; ++kt) {
        __syncthreads();
        {
            const float4* kg4 = (const float4*)(K + boff + (size_t)(kt * 64 + skey) * D_ + sdg * 16);
            const float4 f0 = kg4[0], f1 = kg4[1], f2 = kg4[2], f3 = kg4[3];
            half8_t w0, w1;
            w0[0] = (_Float16)f0.x; w0[1] = (_Float16)f0.y;
            w0[2] = (_Float16)f0.z; w0[3] = (_Float16)f0.w;
            w0[4] = (_Float16)f1.x; w0[5] = (_Float16)f1.y;
            w0[6] = (_Float16)f1.z; w0[7] = (_Float16)f1.w;
            w1[0] = (_Float16)f2.x; w1[1] = (_Float16)f2.y;
            w1[2] = (_Float16)f2.z; w1[3] = (_Float16)f2.w;
            w1[4] = (_Float16)f3.x; w1[5] = (_Float16)f3.y;
            w1[6] = (_Float16)f3.z; w1[7] = (_Float16)f3.w;
            *(half8_t*)&Kt[skey * KS + sdg * 16] = w0;
            *(half8_t*)&Kt[skey * KS + sdg * 16 + 8] = w1;
        }
        {
            const float4* vg4 = (const float4*)(V + boff + (size_t)(kt * 64 + skey) * D_ + sdg * 16);
            #pragma unroll
            for (int i = 0; i < 4; ++i) {
                const float4 f = vg4[i];
                const int d0 = sdg * 16 + i * 4;
                Vt[(d0 + 0) * KS + skey] = (_Float16)f.x;
                Vt[(d0 + 1) * KS + skey] = (_Float16)f.y;
                Vt[(d0 + 2) * KS + skey] = (_Float16)f.z;
                Vt[(d0 + 3) * KS + skey] = (_Float16)f.w;
            }
        }
        __syncthreads();
        #pragma unroll
        for (int s = 0; s < 4; ++s) {
            const half8_t bk0 = *(const half8_t*)&Kt[(s * 16 + l15) * KS + quad * 8];
            const half8_t bk1 = *(const half8_t*)&Kt[(s * 16 + l15) * KS + 32 + quad * 8];
            f32x4 sc = (f32x4){0.f, 0.f, 0.f, 0.f};
            sc = __builtin_amdgcn_mfma_f32_16x16x32_f16(aq[0], bk0, sc, 0, 0, 0);
            sc = __builtin_amdgcn_mfma_f32_16x16x32_f16(aq[1], bk1, sc, 0, 0, 0);
            #pragma unroll
            for (int r = 0; r < 4; ++r) {
                const float p = __expf(sc[r] * 0.125f);
                lacc[r] += p;
                Pw[(quad * 4 + r) * KS + s * 16 + l15] = (_Float16)p;
            }
        }
        __syncthreads();
        #pragma unroll
        for (int c = 0; c < 2; ++c) {
            const half8_t ap = *(const half8_t*)&Pw[l15 * KS + c * 32 + quad * 8];
            #pragma unroll
            for (int d = 0; d < 4; ++d) {
                const half8_t bv = *(const half8_t*)&Vt[(d * 16 + l15) * KS + c * 32 + quad * 8];
                ofr[d] = __builtin_amdgcn_mfma_f32_16x16x32_f16(ap, bv, ofr[d], 0, 0, 0);
            }
        }
    }
    #pragma unroll
    for (int r = 0; r < 4; ++r) {
        float v = lacc[r];
        v += __shfl_xor(v, 1, 64);
        v += __shfl_xor(v, 2, 64);
        v += __shfl_xor(v, 4, 64);
        v += __shfl_xor(v, 8, 64);
        lacc[r] = v;
    }
    #pragma unroll
    for (int r = 0; r < 4; ++r) {
        const float inv = 1.0f / lacc[r];
        float* orow = O + boff + (size_t)(qb + quad * 4 + r) * D_ + l15;
        #pragma unroll
        for (int d = 0; d < 4; ++d) orow[d * 16] = ofr[d][r] * inv;
    }
}

extern "C" void kernel_launch(void* const* d_in, const int* in_sizes, int n_in,
                              void* d_out, int out_size, void* d_ws, size_t ws_size,
                              hipStream_t stream) {
    const float* Q = (const float*)d_in[0];
    const float* K = (const float*)d_in[1];
    const float* V = (const float*)d_in[2];
    float* O = (float*)d_out;

    if (ws_size >= (size_t)8 * 1024 * 1024) {
        _Float16* K16F  = (_Float16*)d_ws;                             // 2 MB
        _Float16* VT16F = K16F + (size_t)1048576;                      // 2 MB
        prepass_frag<<<1024, NT, 0, stream>>>(K, V, K16F, VT16F);
        attn_shared<<<256, 1024, 0, stream>>>(Q, K16F, VT16F, O);
    } else {
        attn_mfma_f16<<<256, NT, 0, stream>>>(Q, K, V, O);
    }
}